// Round 2
// baseline (140.965 us; speedup 1.0000x reference)
//
#include <hip/hip_runtime.h>
#include <hip/hip_bf16.h>

#define IMG 64
#define NPTS 300
#define GRIDN 16
#define BATCH 8

typedef __hip_bfloat16 bf16;

__device__ __forceinline__ float sigm(float x) { return 1.0f / (1.0f + __expf(-x)); }
__device__ __forceinline__ float lo_bf(unsigned u) { return __uint_as_float(u << 16); }
__device__ __forceinline__ float hi_bf(unsigned u) { return __uint_as_float(u & 0xffff0000u); }

template <typename T>
__device__ __forceinline__ float ldv(const void* p, int i);
template <>
__device__ __forceinline__ float ldv<float>(const void* p, int i) { return ((const float*)p)[i]; }
template <>
__device__ __forceinline__ float ldv<bf16>(const void* p, int i) {
    return __bfloat162float(((const bf16*)p)[i]);
}

// Dtype sniffer: first 1800 bf16 slots of W1 (3600 B = full bf16 buffer, half the fp32 one
// -> in-bounds either way). bf16 W1 ~ U(+-0.183) => max ~0.18; fp32 storage read as bf16 has
// random half-words => max >> 4 whp.
__device__ __forceinline__ void sniff(const void* W1, int* sflag, int t) {
    if (t < 64) {
        float m = 0.0f;
        for (int i = t; i < 1800; i += 64) {
            float v = fabsf(__bfloat162float(((const bf16*)W1)[i]));
            if (!(v < 1e30f)) v = 1e30f;
            m = fmaxf(m, v);
        }
#pragma unroll
        for (int d = 1; d < 64; d <<= 1) m = fmaxf(m, __shfl_xor(m, d));
        if (t == 0) *sflag = (m > 4.0f) ? 1 : 0;
    }
}

// ---------------- K1: fully fused MLP -> volume (no K-split, no partial buffer) ----------
// 256 blocks x 512 thr. Block = 64 consecutive W3 columns x all 8 batches (1 output/thread).
// Full h2[8][480] computed redundantly per block (~450 FMA/thread). W3 read exactly once:
// wave lanes = 64 consecutive cols (256 B/row fp32), the 8 waves hit the same lines in L1/L2.
template <typename T>
__device__ void prep_body(const void* zs, const void* b1, const void* W1, const void* W2,
                          const void* b2, const void* W3, const void* b3,
                          bf16* __restrict__ volbf) {
    __shared__ float z[BATCH][30];
    __shared__ float h1[BATCH][60];
    __shared__ __align__(16) float h2[BATCH][480];
    int t = threadIdx.x;  // 0..511

    if (t < 240) {
        int b = t / 30, i = t - b * 30;
        z[b][i] = ldv<T>(zs, t);
    }
    __syncthreads();
    if (t < 480) {
        int b = t / 60, j = t - b * 60;
        float acc = ldv<T>(b1, j);
#pragma unroll
        for (int i = 0; i < 30; ++i) acc = fmaf(z[b][i], ldv<T>(W1, i * 60 + j), acc);
        h1[b][j] = sigm(acc);
    }
    __syncthreads();
    for (int idx = t; idx < BATCH * 480; idx += 512) {
        int b = idx / 480, col = idx - b * 480;
        float acc = ldv<T>(b2, col);
#pragma unroll
        for (int i = 0; i < 60; ++i) acc = fmaf(h1[b][i], ldv<T>(W2, i * 480 + col), acc);
        h2[b][col] = sigm(acc);
    }
    __syncthreads();

    int b = t >> 6;                      // wave-uniform
    int j = blockIdx.x * 64 + (t & 63);  // 64 consecutive columns per block
    float acc = ldv<T>(b3, j);
#pragma unroll 2
    for (int i = 0; i < 480; i += 8) {
        // h2 fragment via 2x ds_read_b128 broadcast (same addr across the wave)
        float4 ha = *(const float4*)&h2[b][i];
        float4 hb = *(const float4*)&h2[b][i + 4];
        acc = fmaf(ha.x, ldv<T>(W3, (size_t)(i + 0) * 16384 + j), acc);
        acc = fmaf(ha.y, ldv<T>(W3, (size_t)(i + 1) * 16384 + j), acc);
        acc = fmaf(ha.z, ldv<T>(W3, (size_t)(i + 2) * 16384 + j), acc);
        acc = fmaf(ha.w, ldv<T>(W3, (size_t)(i + 3) * 16384 + j), acc);
        acc = fmaf(hb.x, ldv<T>(W3, (size_t)(i + 4) * 16384 + j), acc);
        acc = fmaf(hb.y, ldv<T>(W3, (size_t)(i + 5) * 16384 + j), acc);
        acc = fmaf(hb.z, ldv<T>(W3, (size_t)(i + 6) * 16384 + j), acc);
        acc = fmaf(hb.w, ldv<T>(W3, (size_t)(i + 7) * 16384 + j), acc);
    }
    float a = sigm(acc);
    int c = j >> 12, v = j & 4095;  // j = channel*4096 + voxel
    volbf[(size_t)(((b << 12) + v) << 2) + c] = __float2bfloat16(a);
}

__global__ __launch_bounds__(512) void prep_kernel(const void* zs, const void* W1,
                                                   const void* b1, const void* W2,
                                                   const void* b2, const void* W3,
                                                   const void* b3, bf16* __restrict__ volbf,
                                                   int* __restrict__ flag) {
    __shared__ int sflag;
    int t = threadIdx.x;
    sniff(W1, &sflag, t);
    __syncthreads();
    if (blockIdx.x == 0 && t == 0) *flag = sflag;
    if (sflag)
        prep_body<float>(zs, b1, W1, W2, b2, W3, b3, volbf);
    else
        prep_body<bf16>(zs, b1, W1, W2, b2, W3, b3, volbf);
}

// ---------------- K2: ray render ----------------
// 512 blocks x 256 thr. Block = 64 rays of one image; lane = ray*4 + seg (4 depth segments).
// LDS: 4096 voxels x uint2 (4 packed bf16: sigma,r | g,b) = 32 KB.
// Interior fast path: all-8-corners-in-bounds samples (~95%) skip range tests/clamps and use
// one base index + compile-time LDS offsets.
__global__ __launch_bounds__(256) void render_kernel(const void* Rm, const void* Tm,
                                                     const bf16* __restrict__ volbf, void* out,
                                                     const int* __restrict__ flag) {
    __shared__ uint2 vox[4096];
    int t = threadIdx.x;
    int rayBase = blockIdx.x * 64;
    int b = rayBase >> 12;
    const uint2* src = (const uint2*)(volbf + (size_t)b * 4096 * 4);
    for (int i = t; i < 4096; i += 256) vox[i] = src[i];
    __syncthreads();

    int f32out = *flag;
    int ray = rayBase + (t >> 2);
    int seg = t & 3;
    int pix = ray & 4095;
    int h = pix >> 6, w = pix & 63;

    const float inv_f = 0.57735026919f;  // tan(30deg)
    float dcx = (0.984375f - 0.03125f * (float)w) * inv_f;
    float dcy = (0.984375f - 0.03125f * (float)h) * inv_f;

    float R[9], Tv[3];
    if (f32out) {
#pragma unroll
        for (int i = 0; i < 9; ++i) R[i] = ((const float*)Rm)[b * 9 + i];
#pragma unroll
        for (int i = 0; i < 3; ++i) Tv[i] = ((const float*)Tm)[b * 3 + i];
    } else {
#pragma unroll
        for (int i = 0; i < 9; ++i) R[i] = __bfloat162float(((const bf16*)Rm)[b * 9 + i]);
#pragma unroll
        for (int i = 0; i < 3; ++i) Tv[i] = __bfloat162float(((const bf16*)Tm)[b * 3 + i]);
    }

    float dx_ = dcx * R[0] + dcy * R[1] + R[2];
    float dy_ = dcx * R[3] + dcy * R[4] + R[5];
    float dz_ = dcx * R[6] + dcy * R[7] + R[8];
    float ox = -(Tv[0] * R[0] + Tv[1] * R[1] + Tv[2] * R[2]);
    float oy = -(Tv[0] * R[3] + Tv[1] * R[4] + Tv[2] * R[5]);
    float oz = -(Tv[0] * R[6] + Tv[1] * R[7] + Tv[2] * R[8]);

    // slab: contribution possible only while |world coord| < 0.85 on every axis
    // (ix = p*10+7.5 in (-1,16) <=> |p| < 0.85)
    float tA = -1e30f, tB = 1e30f;
    bool miss = false;
    {
        float dd[3] = {dx_, dy_, dz_}, oo[3] = {ox, oy, oz};
#pragma unroll
        for (int a = 0; a < 3; ++a) {
            if (fabsf(dd[a]) > 1e-8f) {
                float inv = 1.0f / dd[a];
                float ra = (-0.85f - oo[a]) * inv, rb = (0.85f - oo[a]) * inv;
                tA = fmaxf(tA, fminf(ra, rb));
                tB = fminf(tB, fmaxf(ra, rb));
            } else if (fabsf(oo[a]) >= 0.85f) {
                miss = true;
            }
        }
    }
    const float step = 2.9f / 299.0f;
    const float inv_step = 299.0f / 2.9f;
    int ilo = 0, ihi = -1;
    if (!miss && tB > tA) {
        float flo = fmaxf(-2.0f, fminf(302.0f, ceilf((tA - 0.1f) * inv_step)));
        float fhi = fmaxf(-2.0f, fminf(302.0f, floorf((tB - 0.1f) * inv_step)));
        ilo = (int)flo - 1;  // widen 1 step each side; out-of-grid samples contribute exactly 0
        ihi = (int)fhi + 1;
        if (ilo < 0) ilo = 0;
        if (ihi > 299) ihi = 299;
    }
    int n = ihi - ilo + 1;
    if (n < 0) n = 0;
    int s0 = ilo + (n * seg) / 4;
    int s1 = ilo + (n * (seg + 1)) / 4;

    float cr = 0.f, cg = 0.f, cb = 0.f, Pa = 1.f;
    for (int i = s0; i < s1; ++i) {
        float tt = 0.1f + step * (float)i;
        float ix = fmaf(fmaf(tt, dx_, ox), 10.0f, 7.5f);
        float iy = fmaf(fmaf(tt, dy_, oy), 10.0f, 7.5f);
        float iz = fmaf(fmaf(tt, dz_, oz), 10.0f, 7.5f);
        float fx = floorf(ix), fy = floorf(iy), fz = floorf(iz);
        float txf = ix - fx, tyf = iy - fy, tzf = iz - fz;
        int x0 = (int)fx, y0 = (int)fy, z0 = (int)fz;

        float sx = 0.f, sr = 0.f, sg = 0.f, sb = 0.f;
        if (((unsigned)x0 < 15u) & ((unsigned)y0 < 15u) & ((unsigned)z0 < 15u)) {
            // fast path: every corner in-bounds; base + immediate LDS offsets
            int base = (z0 << 8) + (y0 << 4) + x0;
            float wx0 = 1.0f - txf, wy0 = 1.0f - tyf, wz0 = 1.0f - tzf;
            float wxy00 = wx0 * wy0, wxy10 = txf * wy0, wxy01 = wx0 * tyf, wxy11 = txf * tyf;
#define CORNF(W, OFF)                          \
    {                                          \
        uint2 q = vox[base + (OFF)];           \
        float wgt_ = (W);                      \
        sx = fmaf(wgt_, lo_bf(q.x), sx);       \
        sr = fmaf(wgt_, hi_bf(q.x), sr);       \
        sg = fmaf(wgt_, lo_bf(q.y), sg);       \
        sb = fmaf(wgt_, hi_bf(q.y), sb);       \
    }
            CORNF(wxy00 * wz0, 0)
            CORNF(wxy10 * wz0, 1)
            CORNF(wxy01 * wz0, 16)
            CORNF(wxy11 * wz0, 17)
            CORNF(wxy00 * tzf, 256)
            CORNF(wxy10 * tzf, 257)
            CORNF(wxy01 * tzf, 272)
            CORNF(wxy11 * tzf, 273)
#undef CORNF
        } else {
            // slow path: boundary samples (clamped indices, zeroed out-of-range weights)
            float wx0 = (x0 >= 0 && x0 <= 15) ? (1.0f - txf) : 0.0f;
            float wx1 = (x0 >= -1 && x0 <= 14) ? txf : 0.0f;
            float wy0 = (y0 >= 0 && y0 <= 15) ? (1.0f - tyf) : 0.0f;
            float wy1 = (y0 >= -1 && y0 <= 14) ? tyf : 0.0f;
            float wz0 = (z0 >= 0 && z0 <= 15) ? (1.0f - tzf) : 0.0f;
            float wz1 = (z0 >= -1 && z0 <= 14) ? tzf : 0.0f;
            int xi0 = min(max(x0, 0), 15), xi1 = min(max(x0 + 1, 0), 15);
            int yi0 = min(max(y0, 0), 15), yi1 = min(max(y0 + 1, 0), 15);
            int zi0 = min(max(z0, 0), 15), zi1 = min(max(z0 + 1, 0), 15);
#define CORN(W, ZI, YI, XI)                              \
    {                                                    \
        uint2 q = vox[((ZI) << 8) + ((YI) << 4) + (XI)]; \
        sx = fmaf((W), lo_bf(q.x), sx);                  \
        sr = fmaf((W), hi_bf(q.x), sr);                  \
        sg = fmaf((W), lo_bf(q.y), sg);                  \
        sb = fmaf((W), hi_bf(q.y), sb);                  \
    }
            float wxy00 = wx0 * wy0, wxy10 = wx1 * wy0, wxy01 = wx0 * wy1, wxy11 = wx1 * wy1;
            CORN(wxy00 * wz0, zi0, yi0, xi0)
            CORN(wxy10 * wz0, zi0, yi0, xi1)
            CORN(wxy01 * wz0, zi0, yi1, xi0)
            CORN(wxy11 * wz0, zi0, yi1, xi1)
            CORN(wxy00 * wz1, zi1, yi0, xi0)
            CORN(wxy10 * wz1, zi1, yi0, xi1)
            CORN(wxy01 * wz1, zi1, yi1, xi0)
            CORN(wxy11 * wz1, zi1, yi1, xi1)
#undef CORN
        }

        float wgt = sx * Pa;
        cr = fmaf(wgt, sr, cr);
        cg = fmaf(wgt, sg, cg);
        cb = fmaf(wgt, sb, cb);
        Pa *= (1.0f - sx);  // 1+1e-10-sx: the 1e-10 vanishes in fp32; opacity prod identical
    }

    // compose the 4 depth segments (ordered) within each 4-lane group
#pragma unroll
    for (int d = 1; d < 4; d <<= 1) {
        float o_cr = __shfl_xor(cr, d);
        float o_cg = __shfl_xor(cg, d);
        float o_cb = __shfl_xor(cb, d);
        float o_Pa = __shfl_xor(Pa, d);
        bool first = ((seg & d) == 0);
        cr = first ? fmaf(Pa, o_cr, cr) : fmaf(o_Pa, cr, o_cr);
        cg = first ? fmaf(Pa, o_cg, cg) : fmaf(o_Pa, cg, o_cg);
        cb = first ? fmaf(Pa, o_cb, cb) : fmaf(o_Pa, cb, o_cb);
        Pa *= o_Pa;
    }

    if (seg == 0) {
        if (f32out) {
            float* of = (float*)out;
            of[ray] = 1.0f - Pa;
            float* orgb = of + BATCH * IMG * IMG;
            orgb[ray * 3 + 0] = cr;
            orgb[ray * 3 + 1] = cg;
            orgb[ray * 3 + 2] = cb;
        } else {
            bf16* ob = (bf16*)out;
            ob[ray] = __float2bfloat16(1.0f - Pa);
            bf16* orgb = ob + BATCH * IMG * IMG;
            orgb[ray * 3 + 0] = __float2bfloat16(cr);
            orgb[ray * 3 + 1] = __float2bfloat16(cg);
            orgb[ray * 3 + 2] = __float2bfloat16(cb);
        }
    }
}

extern "C" void kernel_launch(void* const* d_in, const int* in_sizes, int n_in,
                              void* d_out, int out_size, void* d_ws, size_t ws_size,
                              hipStream_t stream) {
    const void* zs = d_in[0];
    const void* W1 = d_in[1];
    const void* b1 = d_in[2];
    const void* W2 = d_in[3];
    const void* b2 = d_in[4];
    const void* W3 = d_in[5];
    const void* b3 = d_in[6];
    const void* Rm = d_in[7];
    const void* Tm = d_in[8];

    // ws layout: volbf16 [0, 256K) | flag at 256K. (partial buffer eliminated)
    bf16* volbf = (bf16*)d_ws;
    int* flag = (int*)((char*)d_ws + 262144);

    hipLaunchKernelGGL(prep_kernel, dim3(256), dim3(512), 0, stream, zs, W1, b1, W2, b2, W3,
                       b3, volbf, flag);
    hipLaunchKernelGGL(render_kernel, dim3(512), dim3(256), 0, stream, Rm, Tm, volbf, d_out,
                       flag);
}

// Round 3
// 138.066 us; speedup vs baseline: 1.0210x; 1.0210x over previous
//
#include <hip/hip_runtime.h>
#include <hip/hip_bf16.h>

#define IMG 64
#define NPTS 300
#define GRIDN 16
#define BATCH 8

typedef __hip_bfloat16 bf16;

__device__ __forceinline__ float sigm(float x) { return 1.0f / (1.0f + __expf(-x)); }
__device__ __forceinline__ float lo_bf(unsigned u) { return __uint_as_float(u << 16); }
__device__ __forceinline__ float hi_bf(unsigned u) { return __uint_as_float(u & 0xffff0000u); }

template <typename T>
__device__ __forceinline__ float ldv(const void* p, int i);
template <>
__device__ __forceinline__ float ldv<float>(const void* p, int i) { return ((const float*)p)[i]; }
template <>
__device__ __forceinline__ float ldv<bf16>(const void* p, int i) {
    return __bfloat162float(((const bf16*)p)[i]);
}

// Dtype sniffer: first 1800 bf16 slots of W1 (3600 B = full bf16 buffer, half the fp32 one
// -> in-bounds either way). bf16 W1 ~ U(+-0.183) => max ~0.18; fp32 storage read as bf16 has
// random half-words => max >> 4 whp.
__device__ __forceinline__ void sniff(const void* W1, int* sflag, int t) {
    if (t < 64) {
        float m = 0.0f;
        for (int i = t; i < 1800; i += 64) {
            float v = fabsf(__bfloat162float(((const bf16*)W1)[i]));
            if (!(v < 1e30f)) v = 1e30f;
            m = fmaxf(m, v);
        }
#pragma unroll
        for (int d = 1; d < 64; d <<= 1) m = fmaxf(m, __shfl_xor(m, d));
        if (t == 0) *sflag = (m > 4.0f) ? 1 : 0;
    }
}

// ---------------- K1: fully fused MLP -> volume ----------------
// 256 blocks x 512 thr. Block = 64 consecutive W3 columns x 8 batches.
// Phase B thread map: t -> (g = t&7: 8-col group, b = (t>>3)&7: batch, s = t>>6: K-slice of 60
// rows, wave-uniform). Loads are 16 B wide (uint4 of 8 bf16 / 2x float4 for fp32); lanes 0..7
// cover 128 contiguous bytes, the 8 batches re-hit the same line in L1. W3 still read exactly
// once chip-wide. Cross-slice reduction via 16 KB LDS + one barrier.
template <typename T>
__device__ void prep_body(const void* zs, const void* b1, const void* W1, const void* W2,
                          const void* b2, const void* W3, const void* b3,
                          bf16* __restrict__ volbf) {
    __shared__ float z[BATCH][30];
    __shared__ float h1[BATCH][60];
    __shared__ __align__(16) float h2[BATCH][488];  // pad 480->488: 16B-aligned rows, 2-way-max banks
    __shared__ float red[512][8];
    int t = threadIdx.x;  // 0..511

    if (t < 240) {
        int b = t / 30, i = t - b * 30;
        z[b][i] = ldv<T>(zs, t);
    }
    __syncthreads();
    if (t < 480) {
        int b = t / 60, j = t - b * 60;
        float acc = ldv<T>(b1, j);
#pragma unroll
        for (int i = 0; i < 30; ++i) acc = fmaf(z[b][i], ldv<T>(W1, i * 60 + j), acc);
        h1[b][j] = sigm(acc);
    }
    __syncthreads();
    for (int idx = t; idx < BATCH * 480; idx += 512) {
        int b = idx / 480, col = idx - b * 480;
        float acc = ldv<T>(b2, col);
#pragma unroll
        for (int i = 0; i < 60; ++i) acc = fmaf(h1[b][i], ldv<T>(W2, i * 480 + col), acc);
        h2[b][col] = sigm(acc);
    }
    __syncthreads();

    int g = t & 7;         // 8-column group within block
    int b = (t >> 3) & 7;  // batch
    int s = t >> 6;        // K-slice (wave-uniform)
    int j0 = blockIdx.x * 64 + g * 8;
    const float* h2row = &h2[b][s * 60];

    float acc[8];
#pragma unroll
    for (int c = 0; c < 8; ++c) acc[c] = 0.0f;

    if (sizeof(T) == 2) {
        const unsigned short* w3p = (const unsigned short*)W3 + (size_t)(s * 60) * 16384 + j0;
        for (int k = 0; k < 60; k += 4) {
            float4 hv = *(const float4*)(h2row + k);  // ds_read_b128 (16B-aligned)
            float hk[4] = {hv.x, hv.y, hv.z, hv.w};
#pragma unroll
            for (int r = 0; r < 4; ++r) {
                uint4 q = *(const uint4*)(w3p + (size_t)(k + r) * 16384);
                float h = hk[r];
                acc[0] = fmaf(h, lo_bf(q.x), acc[0]);
                acc[1] = fmaf(h, hi_bf(q.x), acc[1]);
                acc[2] = fmaf(h, lo_bf(q.y), acc[2]);
                acc[3] = fmaf(h, hi_bf(q.y), acc[3]);
                acc[4] = fmaf(h, lo_bf(q.z), acc[4]);
                acc[5] = fmaf(h, hi_bf(q.z), acc[5]);
                acc[6] = fmaf(h, lo_bf(q.w), acc[6]);
                acc[7] = fmaf(h, hi_bf(q.w), acc[7]);
            }
        }
    } else {
        const float* w3p = (const float*)W3 + (size_t)(s * 60) * 16384 + j0;
        for (int k = 0; k < 60; k += 4) {
            float4 hv = *(const float4*)(h2row + k);
            float hk[4] = {hv.x, hv.y, hv.z, hv.w};
#pragma unroll
            for (int r = 0; r < 4; ++r) {
                float4 qa = *(const float4*)(w3p + (size_t)(k + r) * 16384);
                float4 qb = *(const float4*)(w3p + (size_t)(k + r) * 16384 + 4);
                float h = hk[r];
                acc[0] = fmaf(h, qa.x, acc[0]);
                acc[1] = fmaf(h, qa.y, acc[1]);
                acc[2] = fmaf(h, qa.z, acc[2]);
                acc[3] = fmaf(h, qa.w, acc[3]);
                acc[4] = fmaf(h, qb.x, acc[4]);
                acc[5] = fmaf(h, qb.y, acc[5]);
                acc[6] = fmaf(h, qb.z, acc[6]);
                acc[7] = fmaf(h, qb.w, acc[7]);
            }
        }
    }

    // stash partials, reduce the 8 K-slices
    *(float4*)&red[t][0] = make_float4(acc[0], acc[1], acc[2], acc[3]);
    *(float4*)&red[t][4] = make_float4(acc[4], acc[5], acc[6], acc[7]);
    __syncthreads();

    int ob = t >> 6, oc = t & 63;  // output: batch ob, column-in-block oc
    int j = blockIdx.x * 64 + oc;
    float a = ldv<T>(b3, j);
#pragma unroll
    for (int ss = 0; ss < 8; ++ss) a += red[(ss << 6) + (ob << 3) + (oc >> 3)][oc & 7];
    a = sigm(a);
    int c = j >> 12, v = j & 4095;  // j = channel*4096 + voxel
    volbf[(size_t)(((ob << 12) + v) << 2) + c] = __float2bfloat16(a);
}

__global__ __launch_bounds__(512) void prep_kernel(const void* zs, const void* W1,
                                                   const void* b1, const void* W2,
                                                   const void* b2, const void* W3,
                                                   const void* b3, bf16* __restrict__ volbf,
                                                   int* __restrict__ flag) {
    __shared__ int sflag;
    int t = threadIdx.x;
    sniff(W1, &sflag, t);
    __syncthreads();
    if (blockIdx.x == 0 && t == 0) *flag = sflag;
    if (sflag)
        prep_body<float>(zs, b1, W1, W2, b2, W3, b3, volbf);
    else
        prep_body<bf16>(zs, b1, W1, W2, b2, W3, b3, volbf);
}

// ---------------- K2: ray render ----------------
// 512 blocks x 256 thr. Block = 64 rays of one image; lane = ray*4 + seg (4 depth segments).
// LDS: 4096 voxels x uint2 (4 packed bf16: sigma,r | g,b) = 32 KB.
// Interior fast path: all-8-corners-in-bounds samples (~95%) skip range tests/clamps and use
// one base index + compile-time LDS offsets.
__global__ __launch_bounds__(256) void render_kernel(const void* Rm, const void* Tm,
                                                     const bf16* __restrict__ volbf, void* out,
                                                     const int* __restrict__ flag) {
    __shared__ uint2 vox[4096];
    int t = threadIdx.x;
    int rayBase = blockIdx.x * 64;
    int b = rayBase >> 12;
    const uint2* src = (const uint2*)(volbf + (size_t)b * 4096 * 4);
    for (int i = t; i < 4096; i += 256) vox[i] = src[i];
    __syncthreads();

    int f32out = *flag;
    int ray = rayBase + (t >> 2);
    int seg = t & 3;
    int pix = ray & 4095;
    int h = pix >> 6, w = pix & 63;

    const float inv_f = 0.57735026919f;  // tan(30deg)
    float dcx = (0.984375f - 0.03125f * (float)w) * inv_f;
    float dcy = (0.984375f - 0.03125f * (float)h) * inv_f;

    float R[9], Tv[3];
    if (f32out) {
#pragma unroll
        for (int i = 0; i < 9; ++i) R[i] = ((const float*)Rm)[b * 9 + i];
#pragma unroll
        for (int i = 0; i < 3; ++i) Tv[i] = ((const float*)Tm)[b * 3 + i];
    } else {
#pragma unroll
        for (int i = 0; i < 9; ++i) R[i] = __bfloat162float(((const bf16*)Rm)[b * 9 + i]);
#pragma unroll
        for (int i = 0; i < 3; ++i) Tv[i] = __bfloat162float(((const bf16*)Tm)[b * 3 + i]);
    }

    float dx_ = dcx * R[0] + dcy * R[1] + R[2];
    float dy_ = dcx * R[3] + dcy * R[4] + R[5];
    float dz_ = dcx * R[6] + dcy * R[7] + R[8];
    float ox = -(Tv[0] * R[0] + Tv[1] * R[1] + Tv[2] * R[2]);
    float oy = -(Tv[0] * R[3] + Tv[1] * R[4] + Tv[2] * R[5]);
    float oz = -(Tv[0] * R[6] + Tv[1] * R[7] + Tv[2] * R[8]);

    // slab: contribution possible only while |world coord| < 0.85 on every axis
    // (ix = p*10+7.5 in (-1,16) <=> |p| < 0.85)
    float tA = -1e30f, tB = 1e30f;
    bool miss = false;
    {
        float dd[3] = {dx_, dy_, dz_}, oo[3] = {ox, oy, oz};
#pragma unroll
        for (int a = 0; a < 3; ++a) {
            if (fabsf(dd[a]) > 1e-8f) {
                float inv = 1.0f / dd[a];
                float ra = (-0.85f - oo[a]) * inv, rb = (0.85f - oo[a]) * inv;
                tA = fmaxf(tA, fminf(ra, rb));
                tB = fminf(tB, fmaxf(ra, rb));
            } else if (fabsf(oo[a]) >= 0.85f) {
                miss = true;
            }
        }
    }
    const float step = 2.9f / 299.0f;
    const float inv_step = 299.0f / 2.9f;
    int ilo = 0, ihi = -1;
    if (!miss && tB > tA) {
        float flo = fmaxf(-2.0f, fminf(302.0f, ceilf((tA - 0.1f) * inv_step)));
        float fhi = fmaxf(-2.0f, fminf(302.0f, floorf((tB - 0.1f) * inv_step)));
        ilo = (int)flo - 1;  // widen 1 step each side; out-of-grid samples contribute exactly 0
        ihi = (int)fhi + 1;
        if (ilo < 0) ilo = 0;
        if (ihi > 299) ihi = 299;
    }
    int n = ihi - ilo + 1;
    if (n < 0) n = 0;
    int s0 = ilo + (n * seg) / 4;
    int s1 = ilo + (n * (seg + 1)) / 4;

    float cr = 0.f, cg = 0.f, cb = 0.f, Pa = 1.f;
    for (int i = s0; i < s1; ++i) {
        float tt = 0.1f + step * (float)i;
        float ix = fmaf(fmaf(tt, dx_, ox), 10.0f, 7.5f);
        float iy = fmaf(fmaf(tt, dy_, oy), 10.0f, 7.5f);
        float iz = fmaf(fmaf(tt, dz_, oz), 10.0f, 7.5f);
        float fx = floorf(ix), fy = floorf(iy), fz = floorf(iz);
        float txf = ix - fx, tyf = iy - fy, tzf = iz - fz;
        int x0 = (int)fx, y0 = (int)fy, z0 = (int)fz;

        float sx = 0.f, sr = 0.f, sg = 0.f, sb = 0.f;
        if (((unsigned)x0 < 15u) & ((unsigned)y0 < 15u) & ((unsigned)z0 < 15u)) {
            // fast path: every corner in-bounds; base + immediate LDS offsets
            int base = (z0 << 8) + (y0 << 4) + x0;
            float wx0 = 1.0f - txf, wy0 = 1.0f - tyf, wz0 = 1.0f - tzf;
            float wxy00 = wx0 * wy0, wxy10 = txf * wy0, wxy01 = wx0 * tyf, wxy11 = txf * tyf;
#define CORNF(W, OFF)                          \
    {                                          \
        uint2 q = vox[base + (OFF)];           \
        float wgt_ = (W);                      \
        sx = fmaf(wgt_, lo_bf(q.x), sx);       \
        sr = fmaf(wgt_, hi_bf(q.x), sr);       \
        sg = fmaf(wgt_, lo_bf(q.y), sg);       \
        sb = fmaf(wgt_, hi_bf(q.y), sb);       \
    }
            CORNF(wxy00 * wz0, 0)
            CORNF(wxy10 * wz0, 1)
            CORNF(wxy01 * wz0, 16)
            CORNF(wxy11 * wz0, 17)
            CORNF(wxy00 * tzf, 256)
            CORNF(wxy10 * tzf, 257)
            CORNF(wxy01 * tzf, 272)
            CORNF(wxy11 * tzf, 273)
#undef CORNF
        } else {
            // slow path: boundary samples (clamped indices, zeroed out-of-range weights)
            float wx0 = (x0 >= 0 && x0 <= 15) ? (1.0f - txf) : 0.0f;
            float wx1 = (x0 >= -1 && x0 <= 14) ? txf : 0.0f;
            float wy0 = (y0 >= 0 && y0 <= 15) ? (1.0f - tyf) : 0.0f;
            float wy1 = (y0 >= -1 && y0 <= 14) ? tyf : 0.0f;
            float wz0 = (z0 >= 0 && z0 <= 15) ? (1.0f - tzf) : 0.0f;
            float wz1 = (z0 >= -1 && z0 <= 14) ? tzf : 0.0f;
            int xi0 = min(max(x0, 0), 15), xi1 = min(max(x0 + 1, 0), 15);
            int yi0 = min(max(y0, 0), 15), yi1 = min(max(y0 + 1, 0), 15);
            int zi0 = min(max(z0, 0), 15), zi1 = min(max(z0 + 1, 0), 15);
#define CORN(W, ZI, YI, XI)                              \
    {                                                    \
        uint2 q = vox[((ZI) << 8) + ((YI) << 4) + (XI)]; \
        sx = fmaf((W), lo_bf(q.x), sx);                  \
        sr = fmaf((W), hi_bf(q.x), sr);                  \
        sg = fmaf((W), lo_bf(q.y), sg);                  \
        sb = fmaf((W), hi_bf(q.y), sb);                  \
    }
            float wxy00 = wx0 * wy0, wxy10 = wx1 * wy0, wxy01 = wx0 * wy1, wxy11 = wx1 * wy1;
            CORN(wxy00 * wz0, zi0, yi0, xi0)
            CORN(wxy10 * wz0, zi0, yi0, xi1)
            CORN(wxy01 * wz0, zi0, yi1, xi0)
            CORN(wxy11 * wz0, zi0, yi1, xi1)
            CORN(wxy00 * wz1, zi1, yi0, xi0)
            CORN(wxy10 * wz1, zi1, yi0, xi1)
            CORN(wxy01 * wz1, zi1, yi1, xi0)
            CORN(wxy11 * wz1, zi1, yi1, xi1)
#undef CORN
        }

        float wgt = sx * Pa;
        cr = fmaf(wgt, sr, cr);
        cg = fmaf(wgt, sg, cg);
        cb = fmaf(wgt, sb, cb);
        Pa *= (1.0f - sx);  // 1+1e-10-sx: the 1e-10 vanishes in fp32; opacity prod identical
    }

    // compose the 4 depth segments (ordered) within each 4-lane group
#pragma unroll
    for (int d = 1; d < 4; d <<= 1) {
        float o_cr = __shfl_xor(cr, d);
        float o_cg = __shfl_xor(cg, d);
        float o_cb = __shfl_xor(cb, d);
        float o_Pa = __shfl_xor(Pa, d);
        bool first = ((seg & d) == 0);
        cr = first ? fmaf(Pa, o_cr, cr) : fmaf(o_Pa, cr, o_cr);
        cg = first ? fmaf(Pa, o_cg, cg) : fmaf(o_Pa, cg, o_cg);
        cb = first ? fmaf(Pa, o_cb, cb) : fmaf(o_Pa, cb, o_cb);
        Pa *= o_Pa;
    }

    if (seg == 0) {
        if (f32out) {
            float* of = (float*)out;
            of[ray] = 1.0f - Pa;
            float* orgb = of + BATCH * IMG * IMG;
            orgb[ray * 3 + 0] = cr;
            orgb[ray * 3 + 1] = cg;
            orgb[ray * 3 + 2] = cb;
        } else {
            bf16* ob = (bf16*)out;
            ob[ray] = __float2bfloat16(1.0f - Pa);
            bf16* orgb = ob + BATCH * IMG * IMG;
            orgb[ray * 3 + 0] = __float2bfloat16(cr);
            orgb[ray * 3 + 1] = __float2bfloat16(cg);
            orgb[ray * 3 + 2] = __float2bfloat16(cb);
        }
    }
}

extern "C" void kernel_launch(void* const* d_in, const int* in_sizes, int n_in,
                              void* d_out, int out_size, void* d_ws, size_t ws_size,
                              hipStream_t stream) {
    const void* zs = d_in[0];
    const void* W1 = d_in[1];
    const void* b1 = d_in[2];
    const void* W2 = d_in[3];
    const void* b2 = d_in[4];
    const void* W3 = d_in[5];
    const void* b3 = d_in[6];
    const void* Rm = d_in[7];
    const void* Tm = d_in[8];

    // ws layout: volbf16 [0, 256K) | flag at 256K. (partial buffer eliminated)
    bf16* volbf = (bf16*)d_ws;
    int* flag = (int*)((char*)d_ws + 262144);

    hipLaunchKernelGGL(prep_kernel, dim3(256), dim3(512), 0, stream, zs, W1, b1, W2, b2, W3,
                       b3, volbf, flag);
    hipLaunchKernelGGL(render_kernel, dim3(512), dim3(256), 0, stream, Rm, Tm, volbf, d_out,
                       flag);
}